// Round 1
// baseline (113.571 us; speedup 1.0000x reference)
//
#include <hip/hip_runtime.h>

// Problem constants (from reference)
#define KSZ   7
#define KK    49          // K*K
#define GCH   16          // group_channels
#define CIN   256
#define MID   64
#define NGRP  16
#define WID   56
#define HWSZ  3136        // 56*56
#define NB    4
#define NPIX  (NB * HWSZ) // 12544
#define EPSV  1e-5f

// ws layout (floats):
// [0..63]    per-channel sum
// [64..127]  per-channel sumsq
// [128..191] a  (gamma * rsqrt(var+eps))
// [192..255] c  (beta - mu*a)
// [256 ...]  t_pre  [B][MID][HW]  (raw conv1+bias, pre-BN)

__global__ __launch_bounds__(256) void k1_conv1(const float* __restrict__ x,
                                                const float* __restrict__ w1,
                                                const float* __restrict__ b1,
                                                float* __restrict__ ws) {
    const int tid = threadIdx.x;
    const int pix = blockIdx.x * 256 + tid;       // 49 blocks * 256 = 12544
    const int ob  = blockIdx.y * 16;              // 4 chunks of 16 mid-channels
    const int b   = pix / HWSZ;
    const int hw  = pix - b * HWSZ;

    float acc[16];
#pragma unroll
    for (int i = 0; i < 16; ++i) acc[i] = b1[ob + i];

    const float* xp = x + (size_t)b * CIN * HWSZ + hw;
#pragma unroll 4
    for (int c = 0; c < CIN; ++c) {
        const float xv = xp[(size_t)c * HWSZ];
#pragma unroll
        for (int i = 0; i < 16; ++i)
            acc[i] = fmaf(w1[(ob + i) * CIN + c], xv, acc[i]);   // uniform -> s_load
    }

    float* tp = ws + 256 + (size_t)b * MID * HWSZ + (size_t)ob * HWSZ + hw;
#pragma unroll
    for (int i = 0; i < 16; ++i) tp[(size_t)i * HWSZ] = acc[i];

    // --- batch stats: wave shuffle reduce, then LDS, then global atomics ---
    __shared__ float bs[16];
    __shared__ float bq[16];
    if (tid < 16) { bs[tid] = 0.f; bq[tid] = 0.f; }
    __syncthreads();

#pragma unroll
    for (int i = 0; i < 16; ++i) {
        float s = acc[i];
        float q = acc[i] * acc[i];
#pragma unroll
        for (int m = 1; m < 64; m <<= 1) {
            s += __shfl_xor(s, m, 64);
            q += __shfl_xor(q, m, 64);
        }
        if ((tid & 63) == 0) {
            atomicAdd(&bs[i], s);
            atomicAdd(&bq[i], q);
        }
    }
    __syncthreads();
    if (tid < 16) {
        atomicAdd(&ws[ob + tid],      bs[tid]);
        atomicAdd(&ws[64 + ob + tid], bq[tid]);
    }
}

__global__ void k2_stats(float* __restrict__ ws,
                         const float* __restrict__ gamma,
                         const float* __restrict__ beta) {
    const int o = threadIdx.x;  // 64 threads
    const float n   = (float)NPIX;
    const float mu  = ws[o] / n;
    const float var = ws[64 + o] / n - mu * mu;
    const float a   = gamma[o] * rsqrtf(var + EPSV);
    ws[128 + o] = a;
    ws[192 + o] = beta[o] - mu * a;
}

__global__ __launch_bounds__(256) void k3_fused(const float* __restrict__ x,
                                                const float* __restrict__ w2,
                                                const float* __restrict__ b2,
                                                const float* __restrict__ ws,
                                                float* __restrict__ out) {
    const int tid = threadIdx.x;
    const int pix = blockIdx.x * 256 + tid;       // 49 blocks * 256
    const int g   = blockIdx.y;                   // group, wave-uniform
    const int b   = pix / HWSZ;
    const int hw  = pix - b * HWSZ;
    const int h   = hw / WID;
    const int w   = hw - h * WID;

    // load t_pre and apply BN (a,c) + ReLU -> tn[64] in VGPRs
    const float* tp = ws + 256 + (size_t)b * MID * HWSZ + hw;
    float tn[MID];
#pragma unroll
    for (int o = 0; o < MID; ++o) {
        const float v = tp[(size_t)o * HWSZ];
        tn[o] = fmaxf(0.f, fmaf(ws[128 + o], v, ws[192 + o]));
    }

    float acc[GCH];
#pragma unroll
    for (int cc = 0; cc < GCH; ++cc) acc[cc] = 0.f;

    const float* xg = x + ((size_t)b * CIN + (size_t)g * GCH) * HWSZ;

    for (int k = 0; k < KK; ++k) {
        const int j = g * KK + k;
        const float* wr = w2 + (size_t)j * MID;   // uniform -> s_load
        float d0 = 0.f, d1 = 0.f, d2 = 0.f, d3 = 0.f;
#pragma unroll
        for (int o = 0; o < MID; o += 4) {
            d0 = fmaf(wr[o    ], tn[o    ], d0);
            d1 = fmaf(wr[o + 1], tn[o + 1], d1);
            d2 = fmaf(wr[o + 2], tn[o + 2], d2);
            d3 = fmaf(wr[o + 3], tn[o + 3], d3);
        }
        const float wgt = b2[j] + ((d0 + d1) + (d2 + d3));

        const int kd = k / 7;
        const int di = kd - 3;
        const int dj = (k - kd * 7) - 3;
        const int hh = h + di;
        const int wwv = w + dj;
        const bool valid = ((unsigned)hh < 56u) && ((unsigned)wwv < 56u);
        const float wm = valid ? wgt : 0.f;
        const int hhc = valid ? hh : 0;
        const int wwc = valid ? wwv : 0;
        const float* xb = xg + hhc * WID + wwc;
#pragma unroll
        for (int cc = 0; cc < GCH; ++cc)
            acc[cc] = fmaf(wm, xb[(size_t)cc * HWSZ], acc[cc]);
    }

    float* ob = out + ((size_t)b * CIN + (size_t)g * GCH) * HWSZ + hw;
#pragma unroll
    for (int cc = 0; cc < GCH; ++cc) ob[(size_t)cc * HWSZ] = acc[cc];
}

extern "C" void kernel_launch(void* const* d_in, const int* in_sizes, int n_in,
                              void* d_out, int out_size, void* d_ws, size_t ws_size,
                              hipStream_t stream) {
    const float* x     = (const float*)d_in[0];
    const float* w1    = (const float*)d_in[1];
    const float* b1    = (const float*)d_in[2];
    const float* gamma = (const float*)d_in[3];
    const float* beta  = (const float*)d_in[4];
    const float* w2    = (const float*)d_in[5];
    const float* b2    = (const float*)d_in[6];
    float* out = (float*)d_out;
    float* ws  = (float*)d_ws;

    // zero the stats accumulators (first 128 floats)
    hipMemsetAsync(ws, 0, 128 * sizeof(float), stream);

    k1_conv1<<<dim3(49, 4), 256, 0, stream>>>(x, w1, b1, ws);
    k2_stats<<<1, 64, 0, stream>>>(ws, gamma, beta);
    k3_fused<<<dim3(49, 16), 256, 0, stream>>>(x, w2, b2, ws, out);
}

// Round 2
// 96.880 us; speedup vs baseline: 1.1723x; 1.1723x over previous
//
#include <hip/hip_runtime.h>

// Problem constants (from reference)
#define KSZ   7
#define KK    49          // K*K
#define GCH   16          // group_channels
#define CIN   256
#define MID   64
#define NGRP  16
#define WID   56
#define HWSZ  3136        // 56*56
#define NB    4
#define NPIX  (NB * HWSZ) // 12544
#define EPSV  1e-5f

// ws layout (floats):
// [0..63]    per-channel sum
// [64..127]  per-channel sumsq
// [128..191] a  (gamma * rsqrt(var+eps))
// [192..255] c  (beta - mu*a)
// [256 ...]  t_pre  [pix][MID]  (TRANSPOSED: 64 contiguous per pixel)

__global__ __launch_bounds__(256, 8) void k1_conv1(const float* __restrict__ x,
                                                   const float* __restrict__ w1,
                                                   const float* __restrict__ b1,
                                                   float* __restrict__ ws) {
    const int tid = threadIdx.x;
    const int pix = blockIdx.x * 256 + tid;       // 49 blocks * 256 = 12544
    const int ob  = blockIdx.y * 4;               // 16 chunks of 4 mid-channels
    const int b   = pix / HWSZ;
    const int hw  = pix - b * HWSZ;

    float acc[4];
#pragma unroll
    for (int i = 0; i < 4; ++i) acc[i] = b1[ob + i];

    const float* xp = x + (size_t)b * CIN * HWSZ + hw;
#pragma unroll 8
    for (int c = 0; c < CIN; ++c) {
        const float xv = xp[(size_t)c * HWSZ];
#pragma unroll
        for (int i = 0; i < 4; ++i)
            acc[i] = fmaf(w1[(ob + i) * CIN + c], xv, acc[i]);   // uniform -> s_load
    }

    // transposed store: t[pix][64]
    float4* tp = (float4*)(ws + 256 + (size_t)pix * MID + ob);
    *tp = make_float4(acc[0], acc[1], acc[2], acc[3]);

    // --- batch stats: wave shuffle reduce, then LDS, then global atomics ---
    __shared__ float bs[4];
    __shared__ float bq[4];
    if (tid < 4) { bs[tid] = 0.f; bq[tid] = 0.f; }
    __syncthreads();

#pragma unroll
    for (int i = 0; i < 4; ++i) {
        float s = acc[i];
        float q = acc[i] * acc[i];
#pragma unroll
        for (int m = 1; m < 64; m <<= 1) {
            s += __shfl_xor(s, m, 64);
            q += __shfl_xor(q, m, 64);
        }
        if ((tid & 63) == 0) {
            atomicAdd(&bs[i], s);
            atomicAdd(&bq[i], q);
        }
    }
    __syncthreads();
    if (tid < 4) {
        atomicAdd(&ws[ob + tid],      bs[tid]);
        atomicAdd(&ws[64 + ob + tid], bq[tid]);
    }
}

__global__ void k2_stats(float* __restrict__ ws,
                         const float* __restrict__ gamma,
                         const float* __restrict__ beta) {
    const int o = threadIdx.x;  // 64 threads
    const float n   = (float)NPIX;
    const float mu  = ws[o] / n;
    const float var = ws[64 + o] / n - mu * mu;
    const float a   = gamma[o] * rsqrtf(var + EPSV);
    ws[128 + o] = a;
    ws[192 + o] = beta[o] - mu * a;
}

__global__ __launch_bounds__(256, 4) void k3_fused(const float* __restrict__ x,
                                                   const float* __restrict__ w2,
                                                   const float* __restrict__ b2,
                                                   const float* __restrict__ ws,
                                                   float* __restrict__ out) {
    const int tid = threadIdx.x;
    const int pix = blockIdx.x * 256 + tid;       // 49 blocks * 256
    const int g   = blockIdx.y;                   // group, wave-uniform
    const int b   = pix / HWSZ;
    const int hw  = pix - b * HWSZ;
    const int h   = hw / WID;
    const int w   = hw - h * WID;

    // load t_pre (transposed, contiguous) and apply BN (a,c) + ReLU -> tn[64]
    const float4* tb = (const float4*)(ws + 256 + (size_t)pix * MID);
    float tn[MID];
#pragma unroll
    for (int i = 0; i < 16; ++i) {
        const float4 v = tb[i];
        const int o = i * 4;
        tn[o + 0] = fmaxf(0.f, fmaf(ws[128 + o + 0], v.x, ws[192 + o + 0]));
        tn[o + 1] = fmaxf(0.f, fmaf(ws[128 + o + 1], v.y, ws[192 + o + 1]));
        tn[o + 2] = fmaxf(0.f, fmaf(ws[128 + o + 2], v.z, ws[192 + o + 2]));
        tn[o + 3] = fmaxf(0.f, fmaf(ws[128 + o + 3], v.w, ws[192 + o + 3]));
    }

    float acc[GCH];
#pragma unroll
    for (int cc = 0; cc < GCH; ++cc) acc[cc] = 0.f;

    const float* xg = x + ((size_t)b * CIN + (size_t)g * GCH) * HWSZ;

    for (int k = 0; k < KK; ++k) {
        const int j = g * KK + k;
        const float* wr = w2 + (size_t)j * MID;   // uniform -> s_load
        float d0 = 0.f, d1 = 0.f, d2 = 0.f, d3 = 0.f;
#pragma unroll
        for (int o = 0; o < MID; o += 4) {
            d0 = fmaf(wr[o    ], tn[o    ], d0);
            d1 = fmaf(wr[o + 1], tn[o + 1], d1);
            d2 = fmaf(wr[o + 2], tn[o + 2], d2);
            d3 = fmaf(wr[o + 3], tn[o + 3], d3);
        }
        const float wgt = b2[j] + ((d0 + d1) + (d2 + d3));

        const int kd = k / 7;
        const int di = kd - 3;
        const int dj = (k - kd * 7) - 3;
        const int hh = h + di;
        const int wwv = w + dj;
        const bool valid = ((unsigned)hh < 56u) && ((unsigned)wwv < 56u);
        const float wm = valid ? wgt : 0.f;
        const int hhc = valid ? hh : 0;
        const int wwc = valid ? wwv : 0;
        const float* xb = xg + hhc * WID + wwc;
#pragma unroll
        for (int cc = 0; cc < GCH; ++cc)
            acc[cc] = fmaf(wm, xb[(size_t)cc * HWSZ], acc[cc]);
    }

    float* ob = out + ((size_t)b * CIN + (size_t)g * GCH) * HWSZ + hw;
#pragma unroll
    for (int cc = 0; cc < GCH; ++cc) ob[(size_t)cc * HWSZ] = acc[cc];
}

extern "C" void kernel_launch(void* const* d_in, const int* in_sizes, int n_in,
                              void* d_out, int out_size, void* d_ws, size_t ws_size,
                              hipStream_t stream) {
    const float* x     = (const float*)d_in[0];
    const float* w1    = (const float*)d_in[1];
    const float* b1    = (const float*)d_in[2];
    const float* gamma = (const float*)d_in[3];
    const float* beta  = (const float*)d_in[4];
    const float* w2    = (const float*)d_in[5];
    const float* b2    = (const float*)d_in[6];
    float* out = (float*)d_out;
    float* ws  = (float*)d_ws;

    // zero the stats accumulators (first 128 floats)
    hipMemsetAsync(ws, 0, 128 * sizeof(float), stream);

    k1_conv1<<<dim3(49, 16), 256, 0, stream>>>(x, w1, b1, ws);
    k2_stats<<<1, 64, 0, stream>>>(ws, gamma, beta);
    k3_fused<<<dim3(49, 16), 256, 0, stream>>>(x, w2, b2, ws, out);
}